// Round 5
// baseline (999.508 us; speedup 1.0000x reference)
//
#include <hip/hip_runtime.h>
#include <hip/hip_bf16.h>
#include <stdint.h>

// DRNN_75204877353433: windowed bidirectional GRU (W=15) + BN + MLP + masked maxpool + linear
// B=32 S=512 W=15 E=300 H=256 V=50000 C=2, G=3H=768

typedef unsigned short u16;
typedef unsigned int u32;
typedef float f32x16 __attribute__((ext_vector_type(16)));
typedef short bf16x8 __attribute__((ext_vector_type(8)));

#define MFMA32 __builtin_amdgcn_mfma_f32_32x32x16_bf16

#define NB 32
#define NS 512
#define NW 15
#define NE 300
#define NH 256
#define NG 768
#define NCELL (NB*NS)   // 16384
#define EPAD 320        // E padded to multiple of 16 for K-loop
#define MR 32           // rows (cells/tokens) per block tile -> 2 blocks/CU

__device__ __forceinline__ float bf2f(u16 u){
    union { unsigned int i; float f; } v; v.i = ((unsigned int)u) << 16; return v.f;
}
__device__ __forceinline__ u16 f2bf(float f){
    union { float f; unsigned int i; } v; v.f = f;
    unsigned int x = v.i;
    x += 0x7fffu + ((x >> 16) & 1u);   // RNE
    return (u16)(x >> 16);
}
__device__ __forceinline__ u16 f2bf_rh(float f){   // round-half-up, 2 VALU ops
    return (u16)((__float_as_uint(f) + 0x8000u) >> 16);
}
__device__ __forceinline__ unsigned fkey(float f){   // order-preserving float->uint map
    unsigned b = __float_as_uint(f);
    return b ^ ((b & 0x80000000u) ? 0xFFFFFFFFu : 0x80000000u);
}

// ---- full-rate gate math (no v_exp/v_rcp/IEEE-div) ----
__device__ __forceinline__ float exp2_poly(float f){   // 2^f, f in [-0.5,0.5], deg-3, err ~1e-4
    float p = 5.58013e-2f;
    p = fmaf(p, f, 2.40028e-1f);
    p = fmaf(p, f, 6.93153e-1f);
    p = fmaf(p, f, 1.0f);
    return p;
}
__device__ __forceinline__ float rcp1p_fast(float d){  // 1/d, d in [1, 2^26]
    float y = __uint_as_float(0x7EF311C3u - __float_as_uint(d));
    y = y * (2.0f - d*y);
    y = y * (2.0f - d*y);
    return y;
}
__device__ __forceinline__ float sigm_fast(float x){   // 1/(1+e^-x)
    float t = x * -1.44269504f;
    t = fminf(fmaxf(t, -25.0f), 25.0f);
    float nf = __builtin_rintf(t);
    float e  = ldexpf(exp2_poly(t - nf), (int)nf);
    return rcp1p_fast(1.0f + e);
}
__device__ __forceinline__ float tanh_fast(float x){   // 2*sigm(2x)-1
    float t = x * -2.88539008f;
    t = fminf(fmaxf(t, -25.0f), 25.0f);
    float nf = __builtin_rintf(t);
    float e  = ldexpf(exp2_poly(t - nf), (int)nf);
    float s  = rcp1p_fast(1.0f + e);
    return fmaf(2.0f, s, -1.0f);
}

// ---------------- prep: bf16 weight conversion + zero-init of accumulators ----------------
__global__ void prep_kernel(const float* __restrict__ Wih_f, const float* __restrict__ Wih_b,
                            const float* __restrict__ Whh_f, const float* __restrict__ Whh_b,
                            const float* __restrict__ mlpW,
                            u16* __restrict__ WihF_p, u16* __restrict__ WihB_p,
                            u16* __restrict__ WhhF_p, u16* __restrict__ WhhB_p,
                            u16* __restrict__ mlpW_p,
                            float* __restrict__ bnSum, float* __restrict__ bnSumSq,
                            unsigned* __restrict__ pooled_u)
{
    const int tid  = blockIdx.x*blockDim.x + threadIdx.x;
    const int nthr = gridDim.x*blockDim.x;
    for (int i = tid; i < NG*EPAD; i += nthr){
        int g = i / EPAD, k = i % EPAD;
        WihF_p[i] = (k < NE) ? f2bf(Wih_f[g*NE + k]) : (u16)0;
        WihB_p[i] = (k < NE) ? f2bf(Wih_b[g*NE + k]) : (u16)0;
    }
    for (int i = tid; i < NG*NH; i += nthr){ WhhF_p[i] = f2bf(Whh_f[i]); WhhB_p[i] = f2bf(Whh_b[i]); }
    for (int i = tid; i < 512*512; i += nthr) mlpW_p[i] = f2bf(mlpW[i]);
    for (int i = tid; i < 512; i += nthr){ bnSum[i] = 0.0f; bnSumSq[i] = 0.0f; }
    for (int i = tid; i < NB*512; i += nthr) pooled_u[i] = 0u;
}

// ---------------- eproj: packed xprojP[row][col][{r,z,n,0}] bf16, b_hh_r/z folded in ----------------
// rows 0..16383 = real tokens, rows 16384..16447 = pad token (id 0)
__global__ __launch_bounds__(512, 4)
void eproj_kernel(const int* __restrict__ x, const float* __restrict__ emb,
                  const u16* __restrict__ Wih_p, const float* __restrict__ b_ih,
                  const float* __restrict__ b_hh, u16* __restrict__ xprojP)
{
    __shared__ u16 a_lds[MR*328];     // 32 rows x 320(+8 pad) bf16 of gathered embeddings
    const int tid = threadIdx.x;
    const int mb  = blockIdx.x;       // 0..513
    {
        const int row = tid >> 4, jj = tid & 15;
        const int flat = mb*MR + row;
        const int t_id = (flat < NCELL) ? x[flat] : 0;
        const float4* src = (const float4*)(emb + (size_t)t_id*NE);
        u16* dst = a_lds + row*328;
        for (int idx = jj; idx < 75; idx += 16){   // 300 floats = 75 float4
            float4 v = src[idx];
            ushort4 o; o.x=f2bf(v.x); o.y=f2bf(v.y); o.z=f2bf(v.z); o.w=f2bf(v.w);
            *(ushort4*)(dst + idx*4) = o;
        }
        if (jj == 15){
            const ushort4 z = {0,0,0,0};
            #pragma unroll
            for (int c = 300; c < 320; c += 4) *(ushort4*)(dst + c) = z;
        }
    }
    __syncthreads();

    const int lane = tid & 63, wv = tid >> 6, l31 = lane & 31, q = lane >> 5;
    const int col = wv*32 + l31;      // hidden column 0..255
    f32x16 acc[3];
    #pragma unroll
    for (int g = 0; g < 3; g++)
        #pragma unroll
        for (int i = 0; i < 16; i++) acc[g][i] = 0.0f;

    const u16* a0p = a_lds + l31*328 + q*8;
    const u16* b0p = Wih_p + (size_t)(         col)*EPAD + q*8;   // gate r plane
    const u16* b1p = Wih_p + (size_t)(NH     + col)*EPAD + q*8;   // gate z plane
    const u16* b2p = Wih_p + (size_t)(2*NH   + col)*EPAD + q*8;   // gate n plane

    #pragma unroll 4
    for (int kc = 0; kc < 20; kc++){
        const int ko = kc*16;
        bf16x8 a0 = *(const bf16x8*)(a0p + ko);
        bf16x8 b0 = *(const bf16x8*)(b0p + ko);
        bf16x8 b1 = *(const bf16x8*)(b1p + ko);
        bf16x8 b2 = *(const bf16x8*)(b2p + ko);
        acc[0] = MFMA32(a0,b0,acc[0],0,0,0);
        acc[1] = MFMA32(a0,b1,acc[1],0,0,0);
        acc[2] = MFMA32(a0,b2,acc[2],0,0,0);
    }
    const float br  = b_ih[col]      + b_hh[col];        // fold recurrent bias (r,z)
    const float bz  = b_ih[NH+col]   + b_hh[NH+col];
    const float bn_ = b_ih[2*NH+col];                    // b_hh_n folded into recur acc init
    #pragma unroll
    for (int r = 0; r < 16; r++){
        const int rit = (r&3) + 8*(r>>2) + 4*q;          // C/D row layout (32x32)
        const int row = mb*MR + rit;
        ushort4 o;
        o.x = f2bf(acc[0][r] + br);
        o.y = f2bf(acc[1][r] + bz);
        o.z = f2bf(acc[2][r] + bn_);
        o.w = 0;
        *(ushort4*)(xprojP + (size_t)row*1024 + col*4) = o;
    }
}

// ---------------- recurrence: per-block 32 cells, 15 GRU steps, h in regs ----------------
// XCD-swizzled grid; double-buffered h LDS (1 barrier/step); xg prefetch across the MFMA
// phase with u32 saddr-form offsets (1 transient VGPR per address -> no round-3 spill).
__global__ __launch_bounds__(512, 4)
void recur_kernel(const int* __restrict__ x, const u16* __restrict__ xprojP,
                  const u16* __restrict__ Whh_p, const float* __restrict__ b_hh,
                  u16* __restrict__ hidden, float* __restrict__ bnSum, float* __restrict__ bnSumSq,
                  int dir)
{
    __shared__ u16 hb[2][MR*264];     // double-buffered 32 x 256(+8 pad) bf16
    __shared__ float maskv[MR];
    const int tid = threadIdx.x;
    const int bid = blockIdx.x;       // 0..511
    const int mb  = ((bid & 7) << 6) | (bid >> 3);   // XCD -> contiguous 2048-row slice
    if (tid < MR) maskv[tid] = (x[mb*MR + tid] > 0) ? 1.0f : 0.0f;
    __syncthreads();

    const int lane = tid & 63, wv = tid >> 6, l31 = lane & 31, q = lane >> 5;
    const int col  = wv*32 + l31;            // hidden column 0..255 (per-lane constant)
    const int bidx = (mb*MR) >> 9;
    const int s0   = (mb*MR) & (NS-1);

    const float bhn = b_hh[2*NH + col];      // only n-gate recurrent bias survives

    const int haOff = l31*264 + q*8;         // LDS A-frag read offset (within buffer)
    // W_hh planes as u32 byte offsets from uniform base (saddr-form loads)
    const char* whbase = (const char*)Whh_p;
    const u32 woff0 = (u32)(( (         col)*NH + q*8) * 2);
    const u32 woff1 = (u32)(( (NH     + col)*NH + q*8) * 2);
    const u32 woff2 = (u32)(( (2*NH   + col)*NH + q*8) * 2);
    // xprojP gate-load base offsets (u32 bytes): row*2048 + col*8
    const char* xbase = (const char*)xprojP;
    const u32 colByte = (u32)(col * 8);
    const u32 rowBase = (u32)(bidx * NS) * 2048u;
    const u32 padOff  = (u32)NCELL * 2048u + colByte;

    float hreg[16];
    #pragma unroll
    for (int i = 0; i < 16; i++) hreg[i] = 0.0f;

    ushort4 xg[16];
    {   // prefetch gate inputs for t=0
        const int sbase = s0 + ((dir == 0) ? -(NW-1) : (NW-1));
        #pragma unroll
        for (int r = 0; r < 16; r++){
            const int rit = (r&3) + 8*(r>>2) + 4*q;
            const int j = sbase + rit;
            const u32 off = ((unsigned)j < (unsigned)NS) ? (rowBase + (u32)j*2048u + colByte) : padOff;
            xg[r] = *(const ushort4*)(xbase + off);
        }
    }

    #pragma unroll 1
    for (int t = 0; t < NW; t++){
        f32x16 acc[3];
        #pragma unroll
        for (int g = 0; g < 3; g++)
            #pragma unroll
            for (int i = 0; i < 16; i++) acc[g][i] = (g == 2) ? bhn : 0.0f;

        if (t > 0){
            const u16* ha0 = hb[t & 1] + haOff;
            #pragma unroll 2
            for (int kc = 0; kc < 16; kc++){
                const int ko = kc*32;    // bytes
                bf16x8 a0 = *(const bf16x8*)(ha0 + kc*16);
                bf16x8 b0 = *(const bf16x8*)(whbase + woff0 + ko);   // W_hh from L2
                bf16x8 b1 = *(const bf16x8*)(whbase + woff1 + ko);
                bf16x8 b2 = *(const bf16x8*)(whbase + woff2 + ko);
                acc[0] = MFMA32(a0,b0,acc[0],0,0,0);
                acc[1] = MFMA32(a0,b1,acc[1],0,0,0);
                acc[2] = MFMA32(a0,b2,acc[2],0,0,0);
            }
        }
        // gate phase — consume prefetched xg, full-rate math
        #pragma unroll
        for (int r = 0; r < 16; r++){
            const float xr = bf2f(xg[r].x), xz = bf2f(xg[r].y), xn = bf2f(xg[r].z);
            const float rg  = sigm_fast(xr + acc[0][r]);
            const float zg  = sigm_fast(xz + acc[1][r]);
            const float ngt = tanh_fast(fmaf(rg, acc[2][r], xn));
            const float hv  = hreg[r];
            hreg[r] = fmaf(zg, hv - ngt, ngt);   // (1-z)n + z h
        }
        // prefetch next step's gate inputs — fly across barrier + next MFMA phase
        if (t + 1 < NW){
            const int sbase = s0 + ((dir == 0) ? (t+1 - (NW-1)) : ((NW-1) - (t+1)));
            #pragma unroll
            for (int r = 0; r < 16; r++){
                const int rit = (r&3) + 8*(r>>2) + 4*q;
                const int j = sbase + rit;
                const u32 off = ((unsigned)j < (unsigned)NS) ? (rowBase + (u32)j*2048u + colByte) : padOff;
                xg[r] = *(const ushort4*)(xbase + off);
            }
            u16* hw = hb[(t + 1) & 1];
            #pragma unroll
            for (int r = 0; r < 16; r++){
                const int rit = (r&3) + 8*(r>>2) + 4*q;
                hw[rit*264 + col] = f2bf_rh(hreg[r]);
            }
            __syncthreads();                 // single barrier per step
        }
    }
    // epilogue: mask, store hidden (bf16), BN partial sums
    float sum = 0.0f, sumsq = 0.0f;
    #pragma unroll
    for (int r = 0; r < 16; r++){
        const int rit = (r&3) + 8*(r>>2) + 4*q;
        const float hm = hreg[r] * maskv[rit];
        hidden[(size_t)(mb*MR + rit)*512 + dir*NH + col] = f2bf(hm);
        sum += hm; sumsq += hm*hm;
    }
    sum   += __shfl_xor(sum, 32);
    sumsq += __shfl_xor(sumsq, 32);
    if (q == 0){
        atomicAdd(&bnSum[dir*NH + col], sum);
        atomicAdd(&bnSumSq[dir*NH + col], sumsq);
    }
}

// ---------------- BN finalize: per-channel scale/shift ----------------
__global__ void bnfin_kernel(const float* __restrict__ bnSum, const float* __restrict__ bnSumSq,
                             const float* __restrict__ gamma, const float* __restrict__ beta,
                             float* __restrict__ bnScale, float* __restrict__ bnShift)
{
    const int c = blockIdx.x*blockDim.x + threadIdx.x;
    if (c < 512){
        const float mu  = bnSum[c]   * (1.0f/16384.0f);
        const float var = bnSumSq[c] * (1.0f/16384.0f) - mu*mu;
        const float inv = rsqrtf(var + 1e-5f);
        const float sc  = gamma[c]*inv;
        bnScale[c] = sc;
        bnShift[c] = beta[c] - mu*sc;
    }
}

// ---------------- MLP + mask + max-pool (atomic ordered-uint max) ----------------
__global__ __launch_bounds__(512, 4)
void mlp_kernel(const int* __restrict__ x, const u16* __restrict__ hidden,
                const u16* __restrict__ mlpW_p, const float* __restrict__ bnScale,
                const float* __restrict__ bnShift, const float* __restrict__ mlp_b,
                unsigned* __restrict__ pooled_u)
{
    __shared__ u16 a_lds[MR*520];   // 32 x 512(+8) bf16 normalized+masked hidden
    __shared__ float maskv[MR];
    const int tid = threadIdx.x;
    const int mb  = blockIdx.x;     // 0..511
    if (tid < MR) maskv[tid] = (x[mb*MR + tid] > 0) ? 1.0f : 0.0f;
    __syncthreads();
    {
        const int row = tid >> 4, jj = tid & 15;
        const float m = maskv[row];
        const u16* src = hidden + (size_t)(mb*MR + row)*512;
        u16* dst = a_lds + row*520;
        for (int c4 = jj; c4 < 128; c4 += 16){
            ushort4 v = ((const ushort4*)src)[c4];
            const int c = c4*4;
            float4 sc = *(const float4*)(bnScale + c);
            float4 sh = *(const float4*)(bnShift + c);
            ushort4 o;
            o.x = f2bf((bf2f(v.x)*sc.x + sh.x)*m);
            o.y = f2bf((bf2f(v.y)*sc.y + sh.y)*m);
            o.z = f2bf((bf2f(v.z)*sc.z + sh.z)*m);
            o.w = f2bf((bf2f(v.w)*sc.w + sh.w)*m);
            *(ushort4*)(dst + c) = o;
        }
    }
    __syncthreads();

    const int lane = tid & 63, wv = tid >> 6, l31 = lane & 31, q = lane >> 5;
    f32x16 acc[2];
    #pragma unroll
    for (int g = 0; g < 2; g++)
        #pragma unroll
        for (int i = 0; i < 16; i++) acc[g][i] = 0.0f;

    const u16* a0p = a_lds + l31*520 + q*8;
    const u16* b0p = mlpW_p + (size_t)(wv*64 +      l31)*512 + q*8;
    const u16* b1p = mlpW_p + (size_t)(wv*64 + 32 + l31)*512 + q*8;

    #pragma unroll 4
    for (int kc = 0; kc < 32; kc++){
        const int ko = kc*16;
        bf16x8 a0 = *(const bf16x8*)(a0p + ko);
        bf16x8 b0 = *(const bf16x8*)(b0p + ko);
        bf16x8 b1 = *(const bf16x8*)(b1p + ko);
        acc[0] = MFMA32(a0,b0,acc[0],0,0,0);
        acc[1] = MFMA32(a0,b1,acc[1],0,0,0);
    }

    const int bidx = mb >> 4;   // 16 row-blocks per batch element
    #pragma unroll
    for (int nt = 0; nt < 2; nt++){
        const int colg = wv*64 + nt*32 + l31;
        const float bias = mlp_b[colg];
        float mx = -3.4e38f;
        #pragma unroll
        for (int r = 0; r < 16; r++){
            const int rit = (r&3) + 8*(r>>2) + 4*q;
            const float m = maskv[rit];
            const float v = (acc[nt][r] + bias)*m + (m - 1.0f)*65500.0f;
            mx = fmaxf(mx, v);
        }
        mx = fmaxf(mx, __shfl_xor(mx, 32));
        if (q == 0) atomicMax(&pooled_u[bidx*512 + colg], fkey(mx));
    }
}

// ---------------- final linear [32x512] @ [512x2] ----------------
__global__ void final_kernel(const unsigned* __restrict__ pooled_u,
                             const float* __restrict__ linW, const float* __restrict__ linb,
                             float* __restrict__ out)
{
    const int b = blockIdx.x;       // 32
    const int lane = threadIdx.x;   // 64
    float s0 = 0.0f, s1 = 0.0f;
    for (int c = lane; c < 512; c += 64){
        const unsigned u = pooled_u[b*512 + c];
        const unsigned bits = (u & 0x80000000u) ? (u ^ 0x80000000u) : ~u;
        const float f = __uint_as_float(bits);
        s0 += f * linW[c];
        s1 += f * linW[512 + c];
    }
    #pragma unroll
    for (int off = 32; off > 0; off >>= 1){
        s0 += __shfl_xor(s0, off);
        s1 += __shfl_xor(s1, off);
    }
    if (lane == 0){ out[2*b] = s0 + linb[0]; out[2*b + 1] = s1 + linb[1]; }
}

extern "C" void kernel_launch(void* const* d_in, const int* in_sizes, int n_in,
                              void* d_out, int out_size, void* d_ws, size_t ws_size,
                              hipStream_t stream)
{
    const int*   x     = (const int*)  d_in[0];
    const float* emb   = (const float*)d_in[5];
    const float* Wih_f = (const float*)d_in[6];
    const float* Whh_f = (const float*)d_in[7];
    const float* bih_f = (const float*)d_in[8];
    const float* bhh_f = (const float*)d_in[9];
    const float* Wih_b = (const float*)d_in[10];
    const float* Whh_b = (const float*)d_in[11];
    const float* bih_b = (const float*)d_in[12];
    const float* bhh_b = (const float*)d_in[13];
    const float* gamma = (const float*)d_in[14];
    const float* beta  = (const float*)d_in[15];
    const float* mlpW  = (const float*)d_in[16];
    const float* mlpb  = (const float*)d_in[17];
    const float* linW  = (const float*)d_in[18];
    const float* linb  = (const float*)d_in[19];
    float* out = (float*)d_out;
    char* ws = (char*)d_ws;

    // workspace layout (~52.8 MB; xprojP packed [row][col][{r,z,n,0}], shared F then B)
    u16*   WihF_p  = (u16*)  (ws + 0);
    u16*   WihB_p  = (u16*)  (ws + 491520);
    u16*   WhhF_p  = (u16*)  (ws + 983040);
    u16*   WhhB_p  = (u16*)  (ws + 1376256);
    u16*   mlpW_p  = (u16*)  (ws + 1769472);
    float* bnSum   = (float*)(ws + 2293760);
    float* bnSumSq = (float*)(ws + 2295808);
    float* bnScale = (float*)(ws + 2297856);
    float* bnShift = (float*)(ws + 2299904);
    unsigned* pooled_u = (unsigned*)(ws + 2301952);
    u16*   hidden  = (u16*)  (ws + 2367488);    // 16384x512 bf16
    u16*   xprojP  = (u16*)  (ws + 19144704);   // 16448x256x4 bf16 packed

    prep_kernel<<<512, 256, 0, stream>>>(Wih_f, Wih_b, Whh_f, Whh_b, mlpW,
                                         WihF_p, WihB_p, WhhF_p, WhhB_p, mlpW_p,
                                         bnSum, bnSumSq, pooled_u);
    // forward direction
    eproj_kernel<<<514, 512, 0, stream>>>(x, emb, WihF_p, bih_f, bhh_f, xprojP);
    recur_kernel<<<512, 512, 0, stream>>>(x, xprojP, WhhF_p, bhh_f, hidden, bnSum, bnSumSq, 0);
    // backward direction (reuses xprojP buffer)
    eproj_kernel<<<514, 512, 0, stream>>>(x, emb, WihB_p, bih_b, bhh_b, xprojP);
    recur_kernel<<<512, 512, 0, stream>>>(x, xprojP, WhhB_p, bhh_b, hidden, bnSum, bnSumSq, 1);

    bnfin_kernel<<<2, 256, 0, stream>>>(bnSum, bnSumSq, gamma, beta, bnScale, bnShift);
    mlp_kernel<<<512, 512, 0, stream>>>(x, hidden, mlpW_p, bnScale, bnShift, mlpb, pooled_u);
    final_kernel<<<32, 64, 0, stream>>>(pooled_u, linW, linb, out);
}

// Round 6
// 762.847 us; speedup vs baseline: 1.3102x; 1.3102x over previous
//
#include <hip/hip_runtime.h>
#include <hip/hip_bf16.h>
#include <stdint.h>

// DRNN_75204877353433: windowed bidirectional GRU (W=15) + BN + MLP + masked maxpool + linear
// B=32 S=512 W=15 E=300 H=256 V=50000 C=2, G=3H=768

typedef unsigned short u16;
typedef unsigned int u32;
typedef float f32x16 __attribute__((ext_vector_type(16)));
typedef float f32x4  __attribute__((ext_vector_type(4)));
typedef short bf16x8 __attribute__((ext_vector_type(8)));

#define MFMA32 __builtin_amdgcn_mfma_f32_32x32x16_bf16
#define MFMA16 __builtin_amdgcn_mfma_f32_16x16x32_bf16

#define NB 32
#define NS 512
#define NW 15
#define NE 300
#define NH 256
#define NG 768
#define NCELL (NB*NS)   // 16384
#define EPAD 320        // E padded to multiple of 16
#define MRE 32          // rows per block in eproj/mlp
#define MRR 64          // rows per block in recur (M=64: halves W_hh L2 traffic)
#define HS 264          // h_lds row stride (u16)

__device__ __forceinline__ float bf2f(u16 u){
    union { unsigned int i; float f; } v; v.i = ((unsigned int)u) << 16; return v.f;
}
__device__ __forceinline__ u16 f2bf(float f){
    union { float f; unsigned int i; } v; v.f = f;
    unsigned int x = v.i;
    x += 0x7fffu + ((x >> 16) & 1u);   // RNE
    return (u16)(x >> 16);
}
__device__ __forceinline__ u16 f2bf_rh(float f){   // round-half-up, 2 VALU ops
    return (u16)((__float_as_uint(f) + 0x8000u) >> 16);
}
__device__ __forceinline__ unsigned fkey(float f){   // order-preserving float->uint map
    unsigned b = __float_as_uint(f);
    return b ^ ((b & 0x80000000u) ? 0xFFFFFFFFu : 0x80000000u);
}

// ---- full-rate gate math (no v_exp/v_rcp/IEEE-div) ----
__device__ __forceinline__ float exp2_poly(float f){   // 2^f, f in [-0.5,0.5], deg-3
    float p = 5.58013e-2f;
    p = fmaf(p, f, 2.40028e-1f);
    p = fmaf(p, f, 6.93153e-1f);
    p = fmaf(p, f, 1.0f);
    return p;
}
__device__ __forceinline__ float rcp1p_fast(float d){  // 1/d, d in [1, 2^26]
    float y = __uint_as_float(0x7EF311C3u - __float_as_uint(d));
    y = y * (2.0f - d*y);
    y = y * (2.0f - d*y);
    return y;
}
__device__ __forceinline__ float sigm_fast(float x){   // 1/(1+e^-x)
    float t = x * -1.44269504f;
    t = fminf(fmaxf(t, -25.0f), 25.0f);
    float nf = __builtin_rintf(t);
    float e  = ldexpf(exp2_poly(t - nf), (int)nf);
    return rcp1p_fast(1.0f + e);
}
__device__ __forceinline__ float tanh_fast(float x){   // 2*sigm(2x)-1
    float t = x * -2.88539008f;
    t = fminf(fmaxf(t, -25.0f), 25.0f);
    float nf = __builtin_rintf(t);
    float e  = ldexpf(exp2_poly(t - nf), (int)nf);
    float s  = rcp1p_fast(1.0f + e);
    return fmaf(2.0f, s, -1.0f);
}

// ---------------- prep ----------------
__global__ void prep_kernel(const float* __restrict__ Wih_f, const float* __restrict__ Wih_b,
                            const float* __restrict__ Whh_f, const float* __restrict__ Whh_b,
                            const float* __restrict__ mlpW,
                            u16* __restrict__ WihF_p, u16* __restrict__ WihB_p,
                            u16* __restrict__ WhhF_p, u16* __restrict__ WhhB_p,
                            u16* __restrict__ mlpW_p,
                            float* __restrict__ bnSum, float* __restrict__ bnSumSq,
                            unsigned* __restrict__ pooled_u)
{
    const int tid  = blockIdx.x*blockDim.x + threadIdx.x;
    const int nthr = gridDim.x*blockDim.x;
    for (int i = tid; i < NG*EPAD; i += nthr){
        int g = i / EPAD, k = i % EPAD;
        WihF_p[i] = (k < NE) ? f2bf(Wih_f[g*NE + k]) : (u16)0;
        WihB_p[i] = (k < NE) ? f2bf(Wih_b[g*NE + k]) : (u16)0;
    }
    for (int i = tid; i < NG*NH; i += nthr){ WhhF_p[i] = f2bf(Whh_f[i]); WhhB_p[i] = f2bf(Whh_b[i]); }
    for (int i = tid; i < 512*512; i += nthr) mlpW_p[i] = f2bf(mlpW[i]);
    for (int i = tid; i < 512; i += nthr){ bnSum[i] = 0.0f; bnSumSq[i] = 0.0f; }
    for (int i = tid; i < NB*512; i += nthr) pooled_u[i] = 0u;
}

// ---------------- eproj: packed xprojP[row][col][{r,z,n,0}] bf16 ----------------
__global__ __launch_bounds__(512, 4)
void eproj_kernel(const int* __restrict__ x, const float* __restrict__ emb,
                  const u16* __restrict__ Wih_p, const float* __restrict__ b_ih,
                  const float* __restrict__ b_hh, u16* __restrict__ xprojP)
{
    __shared__ u16 a_lds[MRE*328];
    const int tid = threadIdx.x;
    const int mb  = blockIdx.x;       // 0..513
    {
        const int row = tid >> 4, jj = tid & 15;
        const int flat = mb*MRE + row;
        const int t_id = (flat < NCELL) ? x[flat] : 0;
        const float4* src = (const float4*)(emb + (size_t)t_id*NE);
        u16* dst = a_lds + row*328;
        for (int idx = jj; idx < 75; idx += 16){
            float4 v = src[idx];
            ushort4 o; o.x=f2bf(v.x); o.y=f2bf(v.y); o.z=f2bf(v.z); o.w=f2bf(v.w);
            *(ushort4*)(dst + idx*4) = o;
        }
        if (jj == 15){
            const ushort4 z = {0,0,0,0};
            #pragma unroll
            for (int c = 300; c < 320; c += 4) *(ushort4*)(dst + c) = z;
        }
    }
    __syncthreads();

    const int lane = tid & 63, wv = tid >> 6, l31 = lane & 31, q = lane >> 5;
    const int col = wv*32 + l31;
    f32x16 acc[3];
    #pragma unroll
    for (int g = 0; g < 3; g++)
        #pragma unroll
        for (int i = 0; i < 16; i++) acc[g][i] = 0.0f;

    const u16* a0p = a_lds + l31*328 + q*8;
    const u16* b0p = Wih_p + (size_t)(         col)*EPAD + q*8;
    const u16* b1p = Wih_p + (size_t)(NH     + col)*EPAD + q*8;
    const u16* b2p = Wih_p + (size_t)(2*NH   + col)*EPAD + q*8;

    #pragma unroll 4
    for (int kc = 0; kc < 20; kc++){
        const int ko = kc*16;
        bf16x8 a0 = *(const bf16x8*)(a0p + ko);
        bf16x8 b0 = *(const bf16x8*)(b0p + ko);
        bf16x8 b1 = *(const bf16x8*)(b1p + ko);
        bf16x8 b2 = *(const bf16x8*)(b2p + ko);
        acc[0] = MFMA32(a0,b0,acc[0],0,0,0);
        acc[1] = MFMA32(a0,b1,acc[1],0,0,0);
        acc[2] = MFMA32(a0,b2,acc[2],0,0,0);
    }
    const float br  = b_ih[col]      + b_hh[col];
    const float bz  = b_ih[NH+col]   + b_hh[NH+col];
    const float bn_ = b_ih[2*NH+col];
    #pragma unroll
    for (int r = 0; r < 16; r++){
        const int rit = (r&3) + 8*(r>>2) + 4*q;
        const int row = mb*MRE + rit;
        ushort4 o;
        o.x = f2bf(acc[0][r] + br);
        o.y = f2bf(acc[1][r] + bz);
        o.z = f2bf(acc[2][r] + bn_);
        o.w = 0;
        *(ushort4*)(xprojP + (size_t)row*1024 + col*4) = o;
    }
}

// ---------------- recurrence v6: 1024-thr block, M=64 cells, 16x16x32 MFMA ----------------
// 16 waves x (16 cols x 3 gates x 4 m-tiles), acc=48 regs; B(W_hh) loads pipelined 1 kc ahead;
// double-buffered h LDS (1 barrier/step); grid 256 = 1 block/CU, 4 waves/SIMD.
__global__ __launch_bounds__(1024, 4)
void recur_kernel(const int* __restrict__ x, const u16* __restrict__ xprojP,
                  const u16* __restrict__ Whh_p, const float* __restrict__ b_hh,
                  u16* __restrict__ hidden, float* __restrict__ bnSum, float* __restrict__ bnSumSq,
                  int dir)
{
    __shared__ u16 hb[2][MRR*HS];     // 2 x 64 x 264 u16 = 67.5 KB
    __shared__ float maskv[MRR];
    const int tid = threadIdx.x;
    const int bid = blockIdx.x;       // 0..255
    const int mb  = ((bid & 7) << 5) | (bid >> 3);   // XCD -> contiguous 2048-row xproj slice
    if (tid < MRR) maskv[tid] = (x[mb*MRR + tid] > 0) ? 1.0f : 0.0f;
    __syncthreads();

    const int lane = tid & 63, wv = tid >> 6;        // wv 0..15
    const int l15 = lane & 15, q = lane >> 4;        // q 0..3
    const int col  = wv*16 + l15;                    // hidden column 0..255
    const int bidx = (mb*MRR) >> 9;
    const int s0   = (mb*MRR) & (NS-1);

    const float bhn = b_hh[2*NH + col];

    // W_hh planes as u32 byte offsets (saddr-form): row (g*256+col), k = kc*32 + q*8
    const char* whbase = (const char*)Whh_p;
    const u32 woff0 = (u32)(((         col)*NH + q*8) * 2);
    const u32 woff1 = (u32)(((NH     + col)*NH + q*8) * 2);
    const u32 woff2 = (u32)(((2*NH   + col)*NH + q*8) * 2);
    // xprojP: row*2048 + col*8 bytes
    const char* xbase = (const char*)xprojP;
    const u32 colByte = (u32)(col * 8);
    const u32 rowBase = (u32)(bidx * NS) * 2048u;
    const u32 padOff  = (u32)NCELL * 2048u + colByte;

    // A-frag LDS offsets: row (mt*16 + l15), k = kc*32 + q*8
    const int haOff = l15*HS + q*8;

    float hreg[16];
    #pragma unroll
    for (int i = 0; i < 16; i++) hreg[i] = 0.0f;

    #pragma unroll 1
    for (int t = 0; t < NW; t++){
        f32x4 acc[4][3];
        #pragma unroll
        for (int mt = 0; mt < 4; mt++)
            #pragma unroll
            for (int g = 0; g < 3; g++)
                #pragma unroll
                for (int i = 0; i < 4; i++) acc[mt][g][i] = (g == 2) ? bhn : 0.0f;

        if (t > 0){
            const u16* hcur = hb[t & 1] + haOff;
            // B pipelined one kc ahead of consumption
            bf16x8 b0 = *(const bf16x8*)(whbase + woff0);
            bf16x8 b1 = *(const bf16x8*)(whbase + woff1);
            bf16x8 b2 = *(const bf16x8*)(whbase + woff2);
            #pragma unroll
            for (int kc = 0; kc < 8; kc++){
                bf16x8 n0, n1, n2;
                if (kc < 7){
                    const int ko = (kc+1)*64;
                    n0 = *(const bf16x8*)(whbase + woff0 + ko);
                    n1 = *(const bf16x8*)(whbase + woff1 + ko);
                    n2 = *(const bf16x8*)(whbase + woff2 + ko);
                }
                bf16x8 a0 = *(const bf16x8*)(hcur + kc*32 +   0);
                bf16x8 a1 = *(const bf16x8*)(hcur + kc*32 + 16*HS);
                bf16x8 a2 = *(const bf16x8*)(hcur + kc*32 + 32*HS);
                bf16x8 a3 = *(const bf16x8*)(hcur + kc*32 + 48*HS);
                acc[0][0] = MFMA16(a0,b0,acc[0][0],0,0,0);
                acc[1][0] = MFMA16(a1,b0,acc[1][0],0,0,0);
                acc[2][0] = MFMA16(a2,b0,acc[2][0],0,0,0);
                acc[3][0] = MFMA16(a3,b0,acc[3][0],0,0,0);
                acc[0][1] = MFMA16(a0,b1,acc[0][1],0,0,0);
                acc[1][1] = MFMA16(a1,b1,acc[1][1],0,0,0);
                acc[2][1] = MFMA16(a2,b1,acc[2][1],0,0,0);
                acc[3][1] = MFMA16(a3,b1,acc[3][1],0,0,0);
                acc[0][2] = MFMA16(a0,b2,acc[0][2],0,0,0);
                acc[1][2] = MFMA16(a1,b2,acc[1][2],0,0,0);
                acc[2][2] = MFMA16(a2,b2,acc[2][2],0,0,0);
                acc[3][2] = MFMA16(a3,b2,acc[3][2],0,0,0);
                if (kc < 7){ b0 = n0; b1 = n1; b2 = n2; }
            }
        }
        // gate phase — batched xg loads (8 live regs), full-rate math
        const int sbase = s0 + ((dir == 0) ? (t - (NW-1)) : ((NW-1) - t)) + q*4;
        #pragma unroll
        for (int mt = 0; mt < 4; mt++){
            ushort4 xgb[4];
            #pragma unroll
            for (int r = 0; r < 4; r++){
                const int j = sbase + mt*16 + r;
                const u32 off = ((unsigned)j < (unsigned)NS) ? (rowBase + (u32)j*2048u + colByte) : padOff;
                xgb[r] = *(const ushort4*)(xbase + off);
            }
            #pragma unroll
            for (int r = 0; r < 4; r++){
                const int i = mt*4 + r;
                const float xr = bf2f(xgb[r].x), xz = bf2f(xgb[r].y), xn = bf2f(xgb[r].z);
                const float rg  = sigm_fast(xr + acc[mt][0][r]);
                const float zg  = sigm_fast(xz + acc[mt][1][r]);
                const float ngt = tanh_fast(fmaf(rg, acc[mt][2][r], xn));
                const float hv  = hreg[i];
                hreg[i] = fmaf(zg, hv - ngt, ngt);
            }
        }
        if (t + 1 < NW){
            u16* hw = hb[(t + 1) & 1];
            #pragma unroll
            for (int mt = 0; mt < 4; mt++)
                #pragma unroll
                for (int r = 0; r < 4; r++){
                    const int rit = mt*16 + q*4 + r;
                    hw[rit*HS + col] = f2bf_rh(hreg[mt*4 + r]);
                }
            __syncthreads();                 // single barrier per step (double buffer)
        }
    }
    // epilogue: mask, store hidden (bf16), BN partial sums
    float sum = 0.0f, sumsq = 0.0f;
    #pragma unroll
    for (int mt = 0; mt < 4; mt++)
        #pragma unroll
        for (int r = 0; r < 4; r++){
            const int rit = mt*16 + q*4 + r;
            const float hm = hreg[mt*4 + r] * maskv[rit];
            hidden[(size_t)(mb*MRR + rit)*512 + dir*NH + col] = f2bf(hm);
            sum += hm; sumsq += hm*hm;
        }
    // reduce across q (lanes l15, l15+16, l15+32, l15+48 share a col)
    sum   += __shfl_xor(sum, 16);   sumsq += __shfl_xor(sumsq, 16);
    sum   += __shfl_xor(sum, 32);   sumsq += __shfl_xor(sumsq, 32);
    if (q == 0){
        atomicAdd(&bnSum[dir*NH + col], sum);
        atomicAdd(&bnSumSq[dir*NH + col], sumsq);
    }
}

// ---------------- BN finalize ----------------
__global__ void bnfin_kernel(const float* __restrict__ bnSum, const float* __restrict__ bnSumSq,
                             const float* __restrict__ gamma, const float* __restrict__ beta,
                             float* __restrict__ bnScale, float* __restrict__ bnShift)
{
    const int c = blockIdx.x*blockDim.x + threadIdx.x;
    if (c < 512){
        const float mu  = bnSum[c]   * (1.0f/16384.0f);
        const float var = bnSumSq[c] * (1.0f/16384.0f) - mu*mu;
        const float inv = rsqrtf(var + 1e-5f);
        const float sc  = gamma[c]*inv;
        bnScale[c] = sc;
        bnShift[c] = beta[c] - mu*sc;
    }
}

// ---------------- MLP + mask + max-pool ----------------
__global__ __launch_bounds__(512, 4)
void mlp_kernel(const int* __restrict__ x, const u16* __restrict__ hidden,
                const u16* __restrict__ mlpW_p, const float* __restrict__ bnScale,
                const float* __restrict__ bnShift, const float* __restrict__ mlp_b,
                unsigned* __restrict__ pooled_u)
{
    __shared__ u16 a_lds[MRE*520];
    __shared__ float maskv[MRE];
    const int tid = threadIdx.x;
    const int mb  = blockIdx.x;     // 0..511
    if (tid < MRE) maskv[tid] = (x[mb*MRE + tid] > 0) ? 1.0f : 0.0f;
    __syncthreads();
    {
        const int row = tid >> 4, jj = tid & 15;
        const float m = maskv[row];
        const u16* src = hidden + (size_t)(mb*MRE + row)*512;
        u16* dst = a_lds + row*520;
        for (int c4 = jj; c4 < 128; c4 += 16){
            ushort4 v = ((const ushort4*)src)[c4];
            const int c = c4*4;
            float4 sc = *(const float4*)(bnScale + c);
            float4 sh = *(const float4*)(bnShift + c);
            ushort4 o;
            o.x = f2bf((bf2f(v.x)*sc.x + sh.x)*m);
            o.y = f2bf((bf2f(v.y)*sc.y + sh.y)*m);
            o.z = f2bf((bf2f(v.z)*sc.z + sh.z)*m);
            o.w = f2bf((bf2f(v.w)*sc.w + sh.w)*m);
            *(ushort4*)(dst + c) = o;
        }
    }
    __syncthreads();

    const int lane = tid & 63, wv = tid >> 6, l31 = lane & 31, q = lane >> 5;
    f32x16 acc[2];
    #pragma unroll
    for (int g = 0; g < 2; g++)
        #pragma unroll
        for (int i = 0; i < 16; i++) acc[g][i] = 0.0f;

    const u16* a0p = a_lds + l31*520 + q*8;
    const u16* b0p = mlpW_p + (size_t)(wv*64 +      l31)*512 + q*8;
    const u16* b1p = mlpW_p + (size_t)(wv*64 + 32 + l31)*512 + q*8;

    #pragma unroll 4
    for (int kc = 0; kc < 32; kc++){
        const int ko = kc*16;
        bf16x8 a0 = *(const bf16x8*)(a0p + ko);
        bf16x8 b0 = *(const bf16x8*)(b0p + ko);
        bf16x8 b1 = *(const bf16x8*)(b1p + ko);
        acc[0] = MFMA32(a0,b0,acc[0],0,0,0);
        acc[1] = MFMA32(a0,b1,acc[1],0,0,0);
    }

    const int bidx = mb >> 4;
    #pragma unroll
    for (int nt = 0; nt < 2; nt++){
        const int colg = wv*64 + nt*32 + l31;
        const float bias = mlp_b[colg];
        float mx = -3.4e38f;
        #pragma unroll
        for (int r = 0; r < 16; r++){
            const int rit = (r&3) + 8*(r>>2) + 4*q;
            const float m = maskv[rit];
            const float v = (acc[nt][r] + bias)*m + (m - 1.0f)*65500.0f;
            mx = fmaxf(mx, v);
        }
        mx = fmaxf(mx, __shfl_xor(mx, 32));
        if (q == 0) atomicMax(&pooled_u[bidx*512 + colg], fkey(mx));
    }
}

// ---------------- final linear [32x512] @ [512x2] ----------------
__global__ void final_kernel(const unsigned* __restrict__ pooled_u,
                             const float* __restrict__ linW, const float* __restrict__ linb,
                             float* __restrict__ out)
{
    const int b = blockIdx.x;       // 32
    const int lane = threadIdx.x;   // 64
    float s0 = 0.0f, s1 = 0.0f;
    for (int c = lane; c < 512; c += 64){
        const unsigned u = pooled_u[b*512 + c];
        const unsigned bits = (u & 0x80000000u) ? (u ^ 0x80000000u) : ~u;
        const float f = __uint_as_float(bits);
        s0 += f * linW[c];
        s1 += f * linW[512 + c];
    }
    #pragma unroll
    for (int off = 32; off > 0; off >>= 1){
        s0 += __shfl_xor(s0, off);
        s1 += __shfl_xor(s1, off);
    }
    if (lane == 0){ out[2*b] = s0 + linb[0]; out[2*b + 1] = s1 + linb[1]; }
}

extern "C" void kernel_launch(void* const* d_in, const int* in_sizes, int n_in,
                              void* d_out, int out_size, void* d_ws, size_t ws_size,
                              hipStream_t stream)
{
    const int*   x     = (const int*)  d_in[0];
    const float* emb   = (const float*)d_in[5];
    const float* Wih_f = (const float*)d_in[6];
    const float* Whh_f = (const float*)d_in[7];
    const float* bih_f = (const float*)d_in[8];
    const float* bhh_f = (const float*)d_in[9];
    const float* Wih_b = (const float*)d_in[10];
    const float* Whh_b = (const float*)d_in[11];
    const float* bih_b = (const float*)d_in[12];
    const float* bhh_b = (const float*)d_in[13];
    const float* gamma = (const float*)d_in[14];
    const float* beta  = (const float*)d_in[15];
    const float* mlpW  = (const float*)d_in[16];
    const float* mlpb  = (const float*)d_in[17];
    const float* linW  = (const float*)d_in[18];
    const float* linb  = (const float*)d_in[19];
    float* out = (float*)d_out;
    char* ws = (char*)d_ws;

    u16*   WihF_p  = (u16*)  (ws + 0);
    u16*   WihB_p  = (u16*)  (ws + 491520);
    u16*   WhhF_p  = (u16*)  (ws + 983040);
    u16*   WhhB_p  = (u16*)  (ws + 1376256);
    u16*   mlpW_p  = (u16*)  (ws + 1769472);
    float* bnSum   = (float*)(ws + 2293760);
    float* bnSumSq = (float*)(ws + 2295808);
    float* bnScale = (float*)(ws + 2297856);
    float* bnShift = (float*)(ws + 2299904);
    unsigned* pooled_u = (unsigned*)(ws + 2301952);
    u16*   hidden  = (u16*)  (ws + 2367488);    // 16384x512 bf16
    u16*   xprojP  = (u16*)  (ws + 19144704);   // 16448x256x4 bf16 packed

    prep_kernel<<<512, 256, 0, stream>>>(Wih_f, Wih_b, Whh_f, Whh_b, mlpW,
                                         WihF_p, WihB_p, WhhF_p, WhhB_p, mlpW_p,
                                         bnSum, bnSumSq, pooled_u);
    // forward direction
    eproj_kernel<<<514, 512, 0, stream>>>(x, emb, WihF_p, bih_f, bhh_f, xprojP);
    recur_kernel<<<256, 1024, 0, stream>>>(x, xprojP, WhhF_p, bhh_f, hidden, bnSum, bnSumSq, 0);
    // backward direction (reuses xprojP buffer)
    eproj_kernel<<<514, 512, 0, stream>>>(x, emb, WihB_p, bih_b, bhh_b, xprojP);
    recur_kernel<<<256, 1024, 0, stream>>>(x, xprojP, WhhB_p, bhh_b, hidden, bnSum, bnSumSq, 1);

    bnfin_kernel<<<2, 256, 0, stream>>>(bnSum, bnSumSq, gamma, beta, bnScale, bnShift);
    mlp_kernel<<<512, 512, 0, stream>>>(x, hidden, mlpW_p, bnScale, bnShift, mlpb, pooled_u);
    final_kernel<<<32, 64, 0, stream>>>(pooled_u, linW, linb, out);
}